// Round 1
// baseline (1466.571 us; speedup 1.0000x reference)
//
#include <hip/hip_runtime.h>

#define NNODES 100000
#define NEDGES 1600000
#define FIN 128
#define FHID 128
#define FOUT 64

typedef unsigned short u16;
typedef unsigned int u32;
typedef __attribute__((ext_vector_type(8))) short short8;
typedef __attribute__((ext_vector_type(4))) float floatx4;

__device__ __forceinline__ u16 f2bf(float f) {
  u32 u = __float_as_uint(f);
  u32 r = (u + 0x7fffu + ((u >> 16) & 1u)) >> 16;   // RNE
  return (u16)r;
}

// ---------------- CSR build: single-pass, global-atomic ----------------
// Device-scope atomicAdd resolves in TCC; 3.2M scattered int atomics are
// op-rate trivial vs the 48 E-scans of the old histogram build.

__global__ __launch_bounds__(256) void zero_kernel(int4* __restrict__ p, int n4) {
  int i = blockIdx.x * 256 + threadIdx.x;
  if (i < n4) p[i] = make_int4(0, 0, 0, 0);
}

// one pass over edges, int4 loads (4 edges/thread -> 4x MLP)
__global__ __launch_bounds__(256) void deg_kernel(const int* __restrict__ src,
                                                  const int* __restrict__ dst,
                                                  int* __restrict__ deg_src,
                                                  int* __restrict__ deg_dst, int E4) {
  int i = blockIdx.x * 256 + threadIdx.x;
  if (i >= E4) return;
  int4 s = ((const int4*)src)[i];
  int4 d = ((const int4*)dst)[i];
  atomicAdd(&deg_src[s.x], 1);
  atomicAdd(&deg_src[s.y], 1);
  atomicAdd(&deg_src[s.z], 1);
  atomicAdd(&deg_src[s.w], 1);
  atomicAdd(&deg_dst[d.x], 1);
  atomicAdd(&deg_dst[d.y], 1);
  atomicAdd(&deg_dst[d.z], 1);
  atomicAdd(&deg_dst[d.w], 1);
}

__global__ __launch_bounds__(256) void norm_kernel(const int* __restrict__ deg_src,
                                                   const int* __restrict__ deg_dst,
                                                   float* __restrict__ norm_src,
                                                   float* __restrict__ norm_dst, int n) {
  int i = blockIdx.x * 256 + threadIdx.x;
  if (i >= n) return;
  norm_src[i] = rsqrtf(fmaxf((float)deg_src[i], 1.0f));
  norm_dst[i] = rsqrtf(fmaxf((float)deg_dst[i], 1.0f));
}

// ---------------- exclusive scan of deg_dst -> offs ----------------
__global__ __launch_bounds__(256) void scan_block_kernel(const int* __restrict__ deg,
                                                         int* __restrict__ offs,
                                                         int* __restrict__ bsums, int n) {
  __shared__ int sh[256];
  int i = blockIdx.x * 256 + threadIdx.x;
  int v = (i < n) ? deg[i] : 0;
  sh[threadIdx.x] = v;
  __syncthreads();
  for (int d = 1; d < 256; d <<= 1) {
    int t = (threadIdx.x >= d) ? sh[threadIdx.x - d] : 0;
    __syncthreads();
    sh[threadIdx.x] += t;
    __syncthreads();
  }
  if (i < n) offs[i] = sh[threadIdx.x] - v;  // exclusive
  if (threadIdx.x == 255) bsums[blockIdx.x] = sh[255];
}

__global__ __launch_bounds__(512) void scan_sums_kernel(int* bsums, int nb) {
  __shared__ int sh[512];
  int v = (threadIdx.x < nb) ? bsums[threadIdx.x] : 0;
  sh[threadIdx.x] = v;
  __syncthreads();
  for (int d = 1; d < 512; d <<= 1) {
    int t = (threadIdx.x >= d) ? sh[threadIdx.x - d] : 0;
    __syncthreads();
    sh[threadIdx.x] += t;
    __syncthreads();
  }
  if (threadIdx.x < nb) bsums[threadIdx.x] = sh[threadIdx.x] - v;  // exclusive
}

__global__ __launch_bounds__(256) void scan_add_kernel(int* __restrict__ offs,
                                                       const int* __restrict__ bsums, int n) {
  int i = blockIdx.x * 256 + threadIdx.x;
  if (i < n) offs[i] += bsums[blockIdx.x];
}

// ---------------- placement: single pass, cursor atomics ----------------
// offs[] starts as exclusive start-offsets; after this kernel it holds
// END offsets (spmm computes beg = end - deg). Positions unique by atomic.
__global__ __launch_bounds__(256) void place_atomic_kernel(const int* __restrict__ src,
                                                           const int* __restrict__ dst,
                                                           int* __restrict__ cur,
                                                           int* __restrict__ csr, int E4) {
  int i = blockIdx.x * 256 + threadIdx.x;
  if (i >= E4) return;
  int4 s = ((const int4*)src)[i];
  int4 d = ((const int4*)dst)[i];
  csr[atomicAdd(&cur[d.x], 1)] = s.x;
  csr[atomicAdd(&cur[d.y], 1)] = s.y;
  csr[atomicAdd(&cur[d.z], 1)] = s.z;
  csr[atomicAdd(&cur[d.w], 1)] = s.w;
}

// ---- MFMA GEMM: Yb[n,c] = bf16( norm[n] * sum_k X[n,k] * W[k,c] ) ----
// 64x64 tile, K=128 in LDS (bf16, padded stride 136 -> 4-bank row rotation).
// 4 waves x 16 rows; A-frags in regs; mfma_f32_16x16x32_bf16, fp32 accum.

#define XP 136   // padded LDS row stride in u16

template <int CTOT, bool IN_BF16>
__global__ __launch_bounds__(256) void gemm_mfma(const void* __restrict__ Xv,
                                                 const float* __restrict__ W,
                                                 const float* __restrict__ norm,
                                                 u16* __restrict__ Y, int nrows) {
  __shared__ u16 Xs[64 * XP];   // 17408 B
  __shared__ u16 Wt[64 * XP];   // 17408 B, Wt[n][k] = W[k][col0+n]
  __shared__ float norm_s[64];
  const int tid = threadIdx.x;
  const int row0 = blockIdx.x * 64;
  const int col0 = blockIdx.y * 64;

  // stage X tile (64 rows x 128 k) as bf16
  if constexpr (IN_BF16) {
    const u16* X = (const u16*)Xv;
    for (int i = tid; i < 64 * 16; i += 256) {       // 16 uint4 per row
      int r = i >> 4, k8 = (i & 15) * 8;
      int gr = row0 + r;
      uint4 v = make_uint4(0u, 0u, 0u, 0u);
      if (gr < nrows) v = *(const uint4*)&X[(size_t)gr * 128 + k8];
      *(uint4*)&Xs[r * XP + k8] = v;
    }
  } else {
    const float* X = (const float*)Xv;
    for (int i = tid; i < 64 * 32; i += 256) {       // 32 float4 per row
      int r = i >> 5, k4 = (i & 31) * 4;
      int gr = row0 + r;
      ushort4 o = make_ushort4(0, 0, 0, 0);
      if (gr < nrows) {
        float4 v = *(const float4*)&X[(size_t)gr * 128 + k4];
        o.x = f2bf(v.x); o.y = f2bf(v.y); o.z = f2bf(v.z); o.w = f2bf(v.w);
      }
      *(ushort4*)&Xs[r * XP + k4] = o;
    }
  }
  // stage W tile transposed (64 cols x 128 k) as bf16
  for (int i = tid; i < 128 * 16; i += 256) {        // K x 16 float4-groups
    int k = i >> 4, c4 = (i & 15) * 4;
    float4 v = *(const float4*)&W[(size_t)k * CTOT + col0 + c4];
    Wt[(c4 + 0) * XP + k] = f2bf(v.x);
    Wt[(c4 + 1) * XP + k] = f2bf(v.y);
    Wt[(c4 + 2) * XP + k] = f2bf(v.z);
    Wt[(c4 + 3) * XP + k] = f2bf(v.w);
  }
  if (tid < 64) norm_s[tid] = (row0 + tid < nrows) ? norm[row0 + tid] : 0.f;
  __syncthreads();

  const int w = tid >> 6, lane = tid & 63;
  const int quad = lane >> 4, r16 = lane & 15;
  const int arow = w * 16 + r16;   // A-fragment row within tile

  short8 a[4];
#pragma unroll
  for (int kc = 0; kc < 4; kc++)
    a[kc] = *(const short8*)&Xs[arow * XP + kc * 32 + quad * 8];

#pragma unroll
  for (int nc = 0; nc < 4; nc++) {
    floatx4 acc = {0.f, 0.f, 0.f, 0.f};
#pragma unroll
    for (int kc = 0; kc < 4; kc++) {
      short8 b = *(const short8*)&Wt[(nc * 16 + r16) * XP + kc * 32 + quad * 8];
      acc = __builtin_amdgcn_mfma_f32_16x16x32_bf16(a[kc], b, acc, 0, 0, 0);
    }
#pragma unroll
    for (int i = 0; i < 4; i++) {
      int lr = w * 16 + quad * 4 + i;     // C/D: row = quad*4+reg, col = r16
      int gr = row0 + lr;
      if (gr < nrows)
        Y[(size_t)gr * CTOT + col0 + nc * 16 + r16] = f2bf(acc[i] * norm_s[lr]);
    }
  }
}

// ---- SpMM: Y[n,:] = relu?( (sum_{e: dst=n} Hb[src[e],:]) * norm_dst[n] + b ) ----
// bf16 gather, fp32 accumulate; output bf16 (mid pipeline) or fp32 (final).
// ends[] holds END offsets (post-place cursors); beg = end - deg.

template <int F, bool RELU, bool OUT_BF16>
__global__ __launch_bounds__(256) void spmm_bf16(const u16* __restrict__ Hb,
                                                 const int* __restrict__ ends,
                                                 const int* __restrict__ deg,
                                                 const int* __restrict__ csr,
                                                 const float* __restrict__ norm_dst,
                                                 const float* __restrict__ bias,
                                                 void* __restrict__ Yv, int n) {
  constexpr int TPN = F / 8;        // threads per node (8 bf16 = 16 B per lane)
  constexpr int NPB = 256 / TPN;    // nodes per block
  int node = blockIdx.x * NPB + threadIdx.x / TPN;
  if (node >= n) return;
  int f0 = (threadIdx.x % TPN) * 8;
  int end = ends[node];
  int beg = end - deg[node];
  float acc[8] = {};
  for (int e = beg; e < end; e++) {
    int s = csr[e];
    uint4 p = *(const uint4*)&Hb[(size_t)s * F + f0];
    acc[0] += __uint_as_float(p.x << 16);
    acc[1] += __uint_as_float(p.x & 0xffff0000u);
    acc[2] += __uint_as_float(p.y << 16);
    acc[3] += __uint_as_float(p.y & 0xffff0000u);
    acc[4] += __uint_as_float(p.z << 16);
    acc[5] += __uint_as_float(p.z & 0xffff0000u);
    acc[6] += __uint_as_float(p.w << 16);
    acc[7] += __uint_as_float(p.w & 0xffff0000u);
  }
  float nd = norm_dst[node];
  float o[8];
#pragma unroll
  for (int i = 0; i < 8; i++) {
    o[i] = fmaf(acc[i], nd, bias[f0 + i]);
    if (RELU) o[i] = fmaxf(o[i], 0.f);
  }
  if constexpr (OUT_BF16) {
    u16* Y = (u16*)Yv;
    uint4 pk;
    pk.x = (u32)f2bf(o[0]) | ((u32)f2bf(o[1]) << 16);
    pk.y = (u32)f2bf(o[2]) | ((u32)f2bf(o[3]) << 16);
    pk.z = (u32)f2bf(o[4]) | ((u32)f2bf(o[5]) << 16);
    pk.w = (u32)f2bf(o[6]) | ((u32)f2bf(o[7]) << 16);
    *(uint4*)&Y[(size_t)node * F + f0] = pk;
  } else {
    float* Y = (float*)Yv;
    *(float4*)&Y[(size_t)node * F + f0] = make_float4(o[0], o[1], o[2], o[3]);
    *(float4*)&Y[(size_t)node * F + f0 + 4] = make_float4(o[4], o[5], o[6], o[7]);
  }
}

// ---------------- driver ----------------

extern "C" void kernel_launch(void* const* d_in, const int* in_sizes, int n_in,
                              void* d_out, int out_size, void* d_ws, size_t ws_size,
                              hipStream_t stream) {
  const int N = NNODES;
  const int E = NEDGES;
  const float* W1 = (const float*)d_in[9];
  const float* b1 = (const float*)d_in[10];
  const float* W2 = (const float*)d_in[11];
  const float* b2 = (const float*)d_in[12];

  char* ws = (char*)d_ws;
  size_t off = 0;
  auto alloc = [&](size_t bytes) -> void* {
    void* p = ws + off;
    off += (bytes + 255) & ~(size_t)255;
    return p;
  };
  int* deg = (int*)alloc((size_t)2 * N * 4);       // deg_src | deg_dst
  int* deg_src = deg;
  int* deg_dst = deg + N;
  float* norm_src = (float*)alloc((size_t)N * 4);
  float* norm_dst = (float*)alloc((size_t)N * 4);
  int* offs = (int*)alloc((size_t)N * 4);          // scan out -> place cursors -> end offsets
  int* bsums = (int*)alloc(512 * 4);
  int* csr = (int*)alloc((size_t)E * 4);
  u16* H = (u16*)alloc((size_t)N * FHID * 2);      // 25.6 MB bf16 gemm output
  u16* T = (u16*)alloc((size_t)N * FHID * 2);      // 25.6 MB bf16 spmm1 output

  const int nb = (N + 255) / 256;       // 391
  const int E4 = E / 4;                 // 400000
  const int eb = (E4 + 255) / 256;      // 1563
  const int gemm_rb = (N + 63) / 64;    // 1563

  for (int g = 0; g < 3; g++) {
    const float* feat = (const float*)d_in[3 * g + 0];
    const int* src = (const int*)d_in[3 * g + 1];
    const int* dst = (const int*)d_in[3 * g + 2];
    float* zout = (float*)d_out + (size_t)g * N * FOUT;

    // ---- CSR build: 2 edge passes + scan, global atomics ----
    zero_kernel<<<(2 * N / 4 + 255) / 256, 256, 0, stream>>>((int4*)deg, 2 * N / 4);
    deg_kernel<<<eb, 256, 0, stream>>>(src, dst, deg_src, deg_dst, E4);
    norm_kernel<<<nb, 256, 0, stream>>>(deg_src, deg_dst, norm_src, norm_dst, N);
    scan_block_kernel<<<nb, 256, 0, stream>>>(deg_dst, offs, bsums, N);
    scan_sums_kernel<<<1, 512, 0, stream>>>(bsums, nb);
    scan_add_kernel<<<nb, 256, 0, stream>>>(offs, bsums, N);
    place_atomic_kernel<<<eb, 256, 0, stream>>>(src, dst, offs, csr, E4);
    // offs now holds END offsets; spmm uses beg = end - deg.

    // ---- layer 1: H = bf16((feat @ W1) * norm_src) ; T = bf16(relu(spmm(H)*nd + b1)) ----
    gemm_mfma<FHID, false><<<dim3(gemm_rb, FHID / 64), 256, 0, stream>>>(
        feat, W1, norm_src, H, N);
    {
      constexpr int NPB = 256 / (FHID / 8);  // 16 nodes/block
      spmm_bf16<FHID, true, true><<<(N + NPB - 1) / NPB, 256, 0, stream>>>(
          H, offs, deg_dst, csr, norm_dst, b1, T, N);
    }

    // ---- layer 2: H = bf16((T @ W2) * norm_src) ; z = spmm(H)*nd + b2 (fp32) ----
    gemm_mfma<FOUT, true><<<dim3(gemm_rb, FOUT / 64), 256, 0, stream>>>(
        T, W2, norm_src, H, N);
    {
      constexpr int NPB = 256 / (FOUT / 8);  // 32 nodes/block
      spmm_bf16<FOUT, false, false><<<(N + NPB - 1) / NPB, 256, 0, stream>>>(
          H, offs, deg_dst, csr, norm_dst, b2, zout, N);
    }
  }
}

// Round 2
// 1028.411 us; speedup vs baseline: 1.4261x; 1.4261x over previous
//
#include <hip/hip_runtime.h>

#define NNODES 100000
#define NEDGES 1600000
#define FIN 128
#define FHID 128
#define FOUT 64

typedef unsigned short u16;
typedef unsigned int u32;
typedef __attribute__((ext_vector_type(8))) short short8;
typedef __attribute__((ext_vector_type(4))) float floatx4;

__device__ __forceinline__ u16 f2bf(float f) {
  u32 u = __float_as_uint(f);
  u32 r = (u + 0x7fffu + ((u >> 16) & 1u)) >> 16;   // RNE
  return (u16)r;
}

// ---------------- CSR build: two-level bucket partition ----------------
// Buckets of 256 nodes (dst>>8, NBUK=391). One histogram pass (391 LDS bins,
// vs old 16-range rescan), scatter into bucket-major packed edges with
// L2-line-filling write runs, then per-bucket localized CSR placement.
// Fixes round-1's 108MB write-allocate blowup from random 4B csr stores.

#define NBUK 391                       // ceil(100000/256)
#define NSL2 250
#define SLICE2 (NEDGES / NSL2)         // 6400, divisible by 4

__global__ __launch_bounds__(256) void zero_kernel(int4* __restrict__ p, int n4) {
  int i = blockIdx.x * 256 + threadIdx.x;
  if (i < n4) p[i] = make_int4(0, 0, 0, 0);
}

// pass 1: per-slice bucket histogram of dst; fold in deg_src global atomics
__global__ __launch_bounds__(256) void bucket_hist_kernel(const int* __restrict__ src,
                                                          const int* __restrict__ dst,
                                                          u32* __restrict__ part,
                                                          int* __restrict__ deg_src, int E) {
  __shared__ u32 h[NBUK];
  const int s = blockIdx.x;
  for (int i = threadIdx.x; i < NBUK; i += 256) h[i] = 0;
  __syncthreads();
  const int e0 = s * SLICE2, e1 = min(e0 + SLICE2, E);
  const int i0 = e0 >> 2, i1 = e1 >> 2;
  for (int i = i0 + threadIdx.x; i < i1; i += 256) {
    int4 dv = ((const int4*)dst)[i];
    int4 sv = ((const int4*)src)[i];
    atomicAdd(&h[(u32)dv.x >> 8], 1u);
    atomicAdd(&h[(u32)dv.y >> 8], 1u);
    atomicAdd(&h[(u32)dv.z >> 8], 1u);
    atomicAdd(&h[(u32)dv.w >> 8], 1u);
    atomicAdd(&deg_src[sv.x], 1);
    atomicAdd(&deg_src[sv.y], 1);
    atomicAdd(&deg_src[sv.z], 1);
    atomicAdd(&deg_src[sv.w], 1);
  }
  __syncthreads();
  for (int i = threadIdx.x; i < NBUK; i += 256) part[(size_t)s * NBUK + i] = h[i];
}

// scan: part[s][b] -> per-slice local prefix; boff[b]=bucket base; bcount[b]=total
__global__ __launch_bounds__(512) void scan_part_kernel(u32* __restrict__ part,
                                                        u32* __restrict__ boff,
                                                        u32* __restrict__ bcount) {
  const int b = threadIdx.x;
  u32 run = 0;
  if (b < NBUK) {
#pragma unroll 5
    for (int s = 0; s < NSL2; s++) {
      u32 v = part[(size_t)s * NBUK + b];   // coalesced across threads
      part[(size_t)s * NBUK + b] = run;
      run += v;
    }
  }
  __shared__ u32 sh[512];
  sh[threadIdx.x] = (b < NBUK) ? run : 0;
  __syncthreads();
  for (int d = 1; d < 512; d <<= 1) {
    u32 t = (threadIdx.x >= d) ? sh[threadIdx.x - d] : 0;
    __syncthreads();
    sh[threadIdx.x] += t;
    __syncthreads();
  }
  if (b < NBUK) {
    boff[b] = sh[threadIdx.x] - run;  // exclusive over buckets
    bcount[b] = run;
  }
}

// pass 2: scatter packed (src<<8)|(dst&255) into bucket-major order
__global__ __launch_bounds__(256) void scatter_kernel(const int* __restrict__ src,
                                                      const int* __restrict__ dst,
                                                      const u32* __restrict__ part,
                                                      const u32* __restrict__ boff,
                                                      u32* __restrict__ pe, int E) {
  __shared__ u32 cur[NBUK];
  const int s = blockIdx.x;
  for (int i = threadIdx.x; i < NBUK; i += 256)
    cur[i] = part[(size_t)s * NBUK + i] + boff[i];
  __syncthreads();
  const int e0 = s * SLICE2, e1 = min(e0 + SLICE2, E);
  const int i0 = e0 >> 2, i1 = e1 >> 2;
  for (int i = i0 + threadIdx.x; i < i1; i += 256) {
    int4 sv = ((const int4*)src)[i];
    int4 dv = ((const int4*)dst)[i];
    u32 p;
    p = atomicAdd(&cur[(u32)dv.x >> 8], 1u); pe[p] = ((u32)sv.x << 8) | ((u32)dv.x & 255u);
    p = atomicAdd(&cur[(u32)dv.y >> 8], 1u); pe[p] = ((u32)sv.y << 8) | ((u32)dv.y & 255u);
    p = atomicAdd(&cur[(u32)dv.z >> 8], 1u); pe[p] = ((u32)sv.z << 8) | ((u32)dv.z & 255u);
    p = atomicAdd(&cur[(u32)dv.w >> 8], 1u); pe[p] = ((u32)sv.w << 8) | ((u32)dv.w & 255u);
  }
}

// pass 3: per-bucket localized CSR build + offs/deg/norm_dst
__global__ __launch_bounds__(256) void bucket_csr_kernel(const u32* __restrict__ pe,
                                                         const u32* __restrict__ boff,
                                                         const u32* __restrict__ bcount,
                                                         int* __restrict__ csr,
                                                         int* __restrict__ offs,
                                                         int* __restrict__ deg_dst,
                                                         float* __restrict__ norm_dst, int n) {
  const int b = blockIdx.x;
  const int beg = (int)boff[b];
  const int cnt = (int)bcount[b];
  __shared__ int h[256], loc[256];
  const int t = threadIdx.x;
  h[t] = 0;
  __syncthreads();
  for (int i = t; i < cnt; i += 256) atomicAdd(&h[pe[beg + i] & 255u], 1);
  __syncthreads();
  const int myc = h[t];
  loc[t] = myc;
  __syncthreads();
  for (int d = 1; d < 256; d <<= 1) {
    int v = (t >= d) ? loc[t - d] : 0;
    __syncthreads();
    loc[t] += v;
    __syncthreads();
  }
  const int start = beg + loc[t] - myc;   // exclusive within bucket
  const int node = b * 256 + t;
  if (node < n) {
    offs[node] = start;
    deg_dst[node] = myc;
    norm_dst[node] = rsqrtf(fmaxf((float)myc, 1.0f));
  }
  __syncthreads();
  h[t] = start;          // cursors
  __syncthreads();
  for (int i = t; i < cnt; i += 256) {
    u32 v = pe[beg + i];
    int p = atomicAdd(&h[v & 255u], 1);
    csr[p] = (int)(v >> 8);     // writes localized to this bucket's ~16KB segment
  }
}

__global__ __launch_bounds__(256) void norm_src_kernel(const int* __restrict__ deg_src,
                                                       float* __restrict__ norm_src, int n) {
  int i = blockIdx.x * 256 + threadIdx.x;
  if (i < n) norm_src[i] = rsqrtf(fmaxf((float)deg_src[i], 1.0f));
}

// ---- MFMA GEMM: Yb[n,c] = bf16( norm[n] * sum_k X[n,k] * W[k,c] ) ----
// 64x64 tile, K=128 in LDS (bf16, padded stride 136 -> 4-bank row rotation).
// 4 waves x 16 rows; A-frags in regs; mfma_f32_16x16x32_bf16, fp32 accum.

#define XP 136   // padded LDS row stride in u16

template <int CTOT, bool IN_BF16>
__global__ __launch_bounds__(256) void gemm_mfma(const void* __restrict__ Xv,
                                                 const float* __restrict__ W,
                                                 const float* __restrict__ norm,
                                                 u16* __restrict__ Y, int nrows) {
  __shared__ u16 Xs[64 * XP];   // 17408 B
  __shared__ u16 Wt[64 * XP];   // 17408 B, Wt[n][k] = W[k][col0+n]
  __shared__ float norm_s[64];
  const int tid = threadIdx.x;
  const int row0 = blockIdx.x * 64;
  const int col0 = blockIdx.y * 64;

  // stage X tile (64 rows x 128 k) as bf16
  if constexpr (IN_BF16) {
    const u16* X = (const u16*)Xv;
    for (int i = tid; i < 64 * 16; i += 256) {       // 16 uint4 per row
      int r = i >> 4, k8 = (i & 15) * 8;
      int gr = row0 + r;
      uint4 v = make_uint4(0u, 0u, 0u, 0u);
      if (gr < nrows) v = *(const uint4*)&X[(size_t)gr * 128 + k8];
      *(uint4*)&Xs[r * XP + k8] = v;
    }
  } else {
    const float* X = (const float*)Xv;
    for (int i = tid; i < 64 * 32; i += 256) {       // 32 float4 per row
      int r = i >> 5, k4 = (i & 31) * 4;
      int gr = row0 + r;
      ushort4 o = make_ushort4(0, 0, 0, 0);
      if (gr < nrows) {
        float4 v = *(const float4*)&X[(size_t)gr * 128 + k4];
        o.x = f2bf(v.x); o.y = f2bf(v.y); o.z = f2bf(v.z); o.w = f2bf(v.w);
      }
      *(ushort4*)&Xs[r * XP + k4] = o;
    }
  }
  // stage W tile transposed (64 cols x 128 k) as bf16
  for (int i = tid; i < 128 * 16; i += 256) {        // K x 16 float4-groups
    int k = i >> 4, c4 = (i & 15) * 4;
    float4 v = *(const float4*)&W[(size_t)k * CTOT + col0 + c4];
    Wt[(c4 + 0) * XP + k] = f2bf(v.x);
    Wt[(c4 + 1) * XP + k] = f2bf(v.y);
    Wt[(c4 + 2) * XP + k] = f2bf(v.z);
    Wt[(c4 + 3) * XP + k] = f2bf(v.w);
  }
  if (tid < 64) norm_s[tid] = (row0 + tid < nrows) ? norm[row0 + tid] : 0.f;
  __syncthreads();

  const int w = tid >> 6, lane = tid & 63;
  const int quad = lane >> 4, r16 = lane & 15;
  const int arow = w * 16 + r16;   // A-fragment row within tile

  short8 a[4];
#pragma unroll
  for (int kc = 0; kc < 4; kc++)
    a[kc] = *(const short8*)&Xs[arow * XP + kc * 32 + quad * 8];

#pragma unroll
  for (int nc = 0; nc < 4; nc++) {
    floatx4 acc = {0.f, 0.f, 0.f, 0.f};
#pragma unroll
    for (int kc = 0; kc < 4; kc++) {
      short8 b = *(const short8*)&Wt[(nc * 16 + r16) * XP + kc * 32 + quad * 8];
      acc = __builtin_amdgcn_mfma_f32_16x16x32_bf16(a[kc], b, acc, 0, 0, 0);
    }
#pragma unroll
    for (int i = 0; i < 4; i++) {
      int lr = w * 16 + quad * 4 + i;     // C/D: row = quad*4+reg, col = r16
      int gr = row0 + lr;
      if (gr < nrows)
        Y[(size_t)gr * CTOT + col0 + nc * 16 + r16] = f2bf(acc[i] * norm_s[lr]);
    }
  }
}

// ---- SpMM: Y[n,:] = relu?( (sum_{e: dst=n} Hb[src[e],:]) * norm_dst[n] + b ) ----
// bf16 gather, fp32 accumulate; output bf16 (mid pipeline) or fp32 (final).

template <int F, bool RELU, bool OUT_BF16>
__global__ __launch_bounds__(256) void spmm_bf16(const u16* __restrict__ Hb,
                                                 const int* __restrict__ offs,
                                                 const int* __restrict__ deg,
                                                 const int* __restrict__ csr,
                                                 const float* __restrict__ norm_dst,
                                                 const float* __restrict__ bias,
                                                 void* __restrict__ Yv, int n) {
  constexpr int TPN = F / 8;        // threads per node (8 bf16 = 16 B per lane)
  constexpr int NPB = 256 / TPN;    // nodes per block
  int node = blockIdx.x * NPB + threadIdx.x / TPN;
  if (node >= n) return;
  int f0 = (threadIdx.x % TPN) * 8;
  int beg = offs[node];
  int end = beg + deg[node];
  float acc[8] = {};
  for (int e = beg; e < end; e++) {
    int s = csr[e];
    uint4 p = *(const uint4*)&Hb[(size_t)s * F + f0];
    acc[0] += __uint_as_float(p.x << 16);
    acc[1] += __uint_as_float(p.x & 0xffff0000u);
    acc[2] += __uint_as_float(p.y << 16);
    acc[3] += __uint_as_float(p.y & 0xffff0000u);
    acc[4] += __uint_as_float(p.z << 16);
    acc[5] += __uint_as_float(p.z & 0xffff0000u);
    acc[6] += __uint_as_float(p.w << 16);
    acc[7] += __uint_as_float(p.w & 0xffff0000u);
  }
  float nd = norm_dst[node];
  float o[8];
#pragma unroll
  for (int i = 0; i < 8; i++) {
    o[i] = fmaf(acc[i], nd, bias[f0 + i]);
    if (RELU) o[i] = fmaxf(o[i], 0.f);
  }
  if constexpr (OUT_BF16) {
    u16* Y = (u16*)Yv;
    uint4 pk;
    pk.x = (u32)f2bf(o[0]) | ((u32)f2bf(o[1]) << 16);
    pk.y = (u32)f2bf(o[2]) | ((u32)f2bf(o[3]) << 16);
    pk.z = (u32)f2bf(o[4]) | ((u32)f2bf(o[5]) << 16);
    pk.w = (u32)f2bf(o[6]) | ((u32)f2bf(o[7]) << 16);
    *(uint4*)&Y[(size_t)node * F + f0] = pk;
  } else {
    float* Y = (float*)Yv;
    *(float4*)&Y[(size_t)node * F + f0] = make_float4(o[0], o[1], o[2], o[3]);
    *(float4*)&Y[(size_t)node * F + f0 + 4] = make_float4(o[4], o[5], o[6], o[7]);
  }
}

// ---------------- driver ----------------

extern "C" void kernel_launch(void* const* d_in, const int* in_sizes, int n_in,
                              void* d_out, int out_size, void* d_ws, size_t ws_size,
                              hipStream_t stream) {
  const int N = NNODES;
  const int E = NEDGES;
  const float* W1 = (const float*)d_in[9];
  const float* b1 = (const float*)d_in[10];
  const float* W2 = (const float*)d_in[11];
  const float* b2 = (const float*)d_in[12];

  char* ws = (char*)d_ws;
  size_t off = 0;
  auto alloc = [&](size_t bytes) -> void* {
    void* p = ws + off;
    off += (bytes + 255) & ~(size_t)255;
    return p;
  };
  int* deg_src = (int*)alloc((size_t)N * 4);
  int* deg_dst = (int*)alloc((size_t)N * 4);
  float* norm_src = (float*)alloc((size_t)N * 4);
  float* norm_dst = (float*)alloc((size_t)N * 4);
  int* offs = (int*)alloc((size_t)N * 4);
  u32* boff = (u32*)alloc((size_t)NBUK * 4);
  u32* bcount = (u32*)alloc((size_t)NBUK * 4);
  int* csr = (int*)alloc((size_t)E * 4);
  u16* H = (u16*)alloc((size_t)N * FHID * 2);      // 25.6 MB bf16 gemm output
  u16* T = (u16*)alloc((size_t)N * FHID * 2);      // 25.6 MB bf16 spmm1 output

  // aliases: part (NSL2*NBUK u32 = 391KB) on H; pe (E u32 = 6.4MB) on T.
  // Both are dead before gemm1/spmm1 write H/T (all CSR kernels precede them).
  u32* part = (u32*)H;
  u32* pe = (u32*)T;

  const int nb = (N + 255) / 256;       // 391
  const int gemm_rb = (N + 63) / 64;    // 1563

  for (int g = 0; g < 3; g++) {
    const float* feat = (const float*)d_in[3 * g + 0];
    const int* src = (const int*)d_in[3 * g + 1];
    const int* dst = (const int*)d_in[3 * g + 2];
    float* zout = (float*)d_out + (size_t)g * N * FOUT;

    // ---- CSR build: bucket partition (2 edge passes + localized placement) ----
    zero_kernel<<<(N / 4 + 255) / 256, 256, 0, stream>>>((int4*)deg_src, N / 4);
    bucket_hist_kernel<<<NSL2, 256, 0, stream>>>(src, dst, part, deg_src, E);
    scan_part_kernel<<<1, 512, 0, stream>>>(part, boff, bcount);
    scatter_kernel<<<NSL2, 256, 0, stream>>>(src, dst, part, boff, pe, E);
    bucket_csr_kernel<<<NBUK, 256, 0, stream>>>(pe, boff, bcount, csr, offs, deg_dst,
                                                norm_dst, N);
    norm_src_kernel<<<nb, 256, 0, stream>>>(deg_src, norm_src, N);

    // ---- layer 1: H = bf16((feat @ W1) * norm_src) ; T = bf16(relu(spmm(H)*nd + b1)) ----
    gemm_mfma<FHID, false><<<dim3(gemm_rb, FHID / 64), 256, 0, stream>>>(
        feat, W1, norm_src, H, N);
    {
      constexpr int NPB = 256 / (FHID / 8);  // 16 nodes/block
      spmm_bf16<FHID, true, true><<<(N + NPB - 1) / NPB, 256, 0, stream>>>(
          H, offs, deg_dst, csr, norm_dst, b1, T, N);
    }

    // ---- layer 2: H = bf16((T @ W2) * norm_src) ; z = spmm(H)*nd + b2 (fp32) ----
    gemm_mfma<FOUT, true><<<dim3(gemm_rb, FOUT / 64), 256, 0, stream>>>(
        T, W2, norm_src, H, N);
    {
      constexpr int NPB = 256 / (FOUT / 8);  // 32 nodes/block
      spmm_bf16<FOUT, false, false><<<(N + NPB - 1) / NPB, 256, 0, stream>>>(
          H, offs, deg_dst, csr, norm_dst, b2, zout, N);
    }
  }
}

// Round 4
// 959.011 us; speedup vs baseline: 1.5293x; 1.0724x over previous
//
#include <hip/hip_runtime.h>

#define NNODES 100000
#define NEDGES 1600000
#define FIN 128
#define FHID 128
#define FOUT 64

typedef unsigned short u16;
typedef unsigned int u32;
typedef __attribute__((ext_vector_type(8))) short short8;
typedef __attribute__((ext_vector_type(4))) float floatx4;

__device__ __forceinline__ u16 f2bf(float f) {
  u32 u = __float_as_uint(f);
  u32 r = (u + 0x7fffu + ((u >> 16) & 1u)) >> 16;   // RNE
  return (u16)r;
}

// ---------------- CSR build: two-level bucket partition ----------------
// Buckets of 256 nodes (dst>>8, NBUK=391). One histogram pass (391 LDS bins),
// scatter into bucket-major packed edges with L2-line-filling write runs,
// then per-bucket localized CSR placement.

#define NBUK 391                       // ceil(100000/256)
#define NSL2 250
#define SLICE2 (NEDGES / NSL2)         // 6400, divisible by 4

__global__ __launch_bounds__(256) void zero_kernel(int4* __restrict__ p, int n4) {
  int i = blockIdx.x * 256 + threadIdx.x;
  if (i < n4) p[i] = make_int4(0, 0, 0, 0);
}

// pass 1: per-slice bucket histogram of dst; fold in deg_src global atomics
__global__ __launch_bounds__(256) void bucket_hist_kernel(const int* __restrict__ src,
                                                          const int* __restrict__ dst,
                                                          u32* __restrict__ part,
                                                          int* __restrict__ deg_src, int E) {
  __shared__ u32 h[NBUK];
  const int s = blockIdx.x;
  for (int i = threadIdx.x; i < NBUK; i += 256) h[i] = 0;
  __syncthreads();
  const int e0 = s * SLICE2, e1 = min(e0 + SLICE2, E);
  const int i0 = e0 >> 2, i1 = e1 >> 2;
  for (int i = i0 + threadIdx.x; i < i1; i += 256) {
    int4 dv = ((const int4*)dst)[i];
    int4 sv = ((const int4*)src)[i];
    atomicAdd(&h[(u32)dv.x >> 8], 1u);
    atomicAdd(&h[(u32)dv.y >> 8], 1u);
    atomicAdd(&h[(u32)dv.z >> 8], 1u);
    atomicAdd(&h[(u32)dv.w >> 8], 1u);
    atomicAdd(&deg_src[sv.x], 1);
    atomicAdd(&deg_src[sv.y], 1);
    atomicAdd(&deg_src[sv.z], 1);
    atomicAdd(&deg_src[sv.w], 1);
  }
  __syncthreads();
  for (int i = threadIdx.x; i < NBUK; i += 256) part[(size_t)s * NBUK + i] = h[i];
}

// scan: part[s][b] -> per-slice local prefix; boff[b]=bucket base; bcount[b]=total
__global__ __launch_bounds__(512) void scan_part_kernel(u32* __restrict__ part,
                                                        u32* __restrict__ boff,
                                                        u32* __restrict__ bcount) {
  const int b = threadIdx.x;
  u32 run = 0;
  if (b < NBUK) {
#pragma unroll 5
    for (int s = 0; s < NSL2; s++) {
      u32 v = part[(size_t)s * NBUK + b];   // coalesced across threads
      part[(size_t)s * NBUK + b] = run;
      run += v;
    }
  }
  __shared__ u32 sh[512];
  sh[threadIdx.x] = (b < NBUK) ? run : 0;
  __syncthreads();
  for (int d = 1; d < 512; d <<= 1) {
    u32 t = (threadIdx.x >= d) ? sh[threadIdx.x - d] : 0;
    __syncthreads();
    sh[threadIdx.x] += t;
    __syncthreads();
  }
  if (b < NBUK) {
    boff[b] = sh[threadIdx.x] - run;  // exclusive over buckets
    bcount[b] = run;
  }
}

// pass 2: scatter packed (src<<8)|(dst&255) into bucket-major order
__global__ __launch_bounds__(256) void scatter_kernel(const int* __restrict__ src,
                                                      const int* __restrict__ dst,
                                                      const u32* __restrict__ part,
                                                      const u32* __restrict__ boff,
                                                      u32* __restrict__ pe, int E) {
  __shared__ u32 cur[NBUK];
  const int s = blockIdx.x;
  for (int i = threadIdx.x; i < NBUK; i += 256)
    cur[i] = part[(size_t)s * NBUK + i] + boff[i];
  __syncthreads();
  const int e0 = s * SLICE2, e1 = min(e0 + SLICE2, E);
  const int i0 = e0 >> 2, i1 = e1 >> 2;
  for (int i = i0 + threadIdx.x; i < i1; i += 256) {
    int4 sv = ((const int4*)src)[i];
    int4 dv = ((const int4*)dst)[i];
    u32 p;
    p = atomicAdd(&cur[(u32)dv.x >> 8], 1u); pe[p] = ((u32)sv.x << 8) | ((u32)dv.x & 255u);
    p = atomicAdd(&cur[(u32)dv.y >> 8], 1u); pe[p] = ((u32)sv.y << 8) | ((u32)dv.y & 255u);
    p = atomicAdd(&cur[(u32)dv.z >> 8], 1u); pe[p] = ((u32)sv.z << 8) | ((u32)dv.z & 255u);
    p = atomicAdd(&cur[(u32)dv.w >> 8], 1u); pe[p] = ((u32)sv.w << 8) | ((u32)dv.w & 255u);
  }
}

// pass 3: per-bucket localized CSR build + offs/deg/norm_dst
__global__ __launch_bounds__(256) void bucket_csr_kernel(const u32* __restrict__ pe,
                                                         const u32* __restrict__ boff,
                                                         const u32* __restrict__ bcount,
                                                         int* __restrict__ csr,
                                                         int* __restrict__ offs,
                                                         int* __restrict__ deg_dst,
                                                         float* __restrict__ norm_dst, int n) {
  const int b = blockIdx.x;
  const int beg = (int)boff[b];
  const int cnt = (int)bcount[b];
  __shared__ int h[256], loc[256];
  const int t = threadIdx.x;
  h[t] = 0;
  __syncthreads();
  for (int i = t; i < cnt; i += 256) atomicAdd(&h[pe[beg + i] & 255u], 1);
  __syncthreads();
  const int myc = h[t];
  loc[t] = myc;
  __syncthreads();
  for (int d = 1; d < 256; d <<= 1) {
    int v = (t >= d) ? loc[t - d] : 0;
    __syncthreads();
    loc[t] += v;
    __syncthreads();
  }
  const int start = beg + loc[t] - myc;   // exclusive within bucket
  const int node = b * 256 + t;
  if (node < n) {
    offs[node] = start;
    deg_dst[node] = myc;
    norm_dst[node] = rsqrtf(fmaxf((float)myc, 1.0f));
  }
  __syncthreads();
  h[t] = start;          // cursors
  __syncthreads();
  for (int i = t; i < cnt; i += 256) {
    u32 v = pe[beg + i];
    int p = atomicAdd(&h[v & 255u], 1);
    csr[p] = (int)(v >> 8);     // writes localized to this bucket's ~16KB segment
  }
}

__global__ __launch_bounds__(256) void norm_src_kernel(const int* __restrict__ deg_src,
                                                       float* __restrict__ norm_src, int n) {
  int i = blockIdx.x * 256 + threadIdx.x;
  if (i < n) norm_src[i] = rsqrtf(fmaxf((float)deg_src[i], 1.0f));
}

// ---- MFMA GEMM: Yb[n,c] = bf16( norm[n] * sum_k X[n,k] * W[k,c] ) ----
// 64x64 tile, K=128 in LDS (bf16, padded stride 136 -> 4-bank row rotation).
// 4 waves x 16 rows; A-frags in regs; mfma_f32_16x16x32_bf16, fp32 accum.

#define XP 136   // padded LDS row stride in u16

template <int CTOT, bool IN_BF16>
__global__ __launch_bounds__(256) void gemm_mfma(const void* __restrict__ Xv,
                                                 const float* __restrict__ W,
                                                 const float* __restrict__ norm,
                                                 u16* __restrict__ Y, int nrows) {
  __shared__ u16 Xs[64 * XP];   // 17408 B
  __shared__ u16 Wt[64 * XP];   // 17408 B, Wt[n][k] = W[k][col0+n]
  __shared__ float norm_s[64];
  const int tid = threadIdx.x;
  const int row0 = blockIdx.x * 64;
  const int col0 = blockIdx.y * 64;

  // stage X tile (64 rows x 128 k) as bf16
  if constexpr (IN_BF16) {
    const u16* X = (const u16*)Xv;
    for (int i = tid; i < 64 * 16; i += 256) {       // 16 uint4 per row
      int r = i >> 4, k8 = (i & 15) * 8;
      int gr = row0 + r;
      uint4 v = make_uint4(0u, 0u, 0u, 0u);
      if (gr < nrows) v = *(const uint4*)&X[(size_t)gr * 128 + k8];
      *(uint4*)&Xs[r * XP + k8] = v;
    }
  } else {
    const float* X = (const float*)Xv;
    for (int i = tid; i < 64 * 32; i += 256) {       // 32 float4 per row
      int r = i >> 5, k4 = (i & 31) * 4;
      int gr = row0 + r;
      ushort4 o = make_ushort4(0, 0, 0, 0);
      if (gr < nrows) {
        float4 v = *(const float4*)&X[(size_t)gr * 128 + k4];
        o.x = f2bf(v.x); o.y = f2bf(v.y); o.z = f2bf(v.z); o.w = f2bf(v.w);
      }
      *(ushort4*)&Xs[r * XP + k4] = o;
    }
  }
  // stage W tile transposed (64 cols x 128 k) as bf16
  for (int i = tid; i < 128 * 16; i += 256) {        // K x 16 float4-groups
    int k = i >> 4, c4 = (i & 15) * 4;
    float4 v = *(const float4*)&W[(size_t)k * CTOT + col0 + c4];
    Wt[(c4 + 0) * XP + k] = f2bf(v.x);
    Wt[(c4 + 1) * XP + k] = f2bf(v.y);
    Wt[(c4 + 2) * XP + k] = f2bf(v.z);
    Wt[(c4 + 3) * XP + k] = f2bf(v.w);
  }
  if (tid < 64) norm_s[tid] = (row0 + tid < nrows) ? norm[row0 + tid] : 0.f;
  __syncthreads();

  const int w = tid >> 6, lane = tid & 63;
  const int quad = lane >> 4, r16 = lane & 15;
  const int arow = w * 16 + r16;   // A-fragment row within tile

  short8 a[4];
#pragma unroll
  for (int kc = 0; kc < 4; kc++)
    a[kc] = *(const short8*)&Xs[arow * XP + kc * 32 + quad * 8];

#pragma unroll
  for (int nc = 0; nc < 4; nc++) {
    floatx4 acc = {0.f, 0.f, 0.f, 0.f};
#pragma unroll
    for (int kc = 0; kc < 4; kc++) {
      short8 b = *(const short8*)&Wt[(nc * 16 + r16) * XP + kc * 32 + quad * 8];
      acc = __builtin_amdgcn_mfma_f32_16x16x32_bf16(a[kc], b, acc, 0, 0, 0);
    }
#pragma unroll
    for (int i = 0; i < 4; i++) {
      int lr = w * 16 + quad * 4 + i;     // C/D: row = quad*4+reg, col = r16
      int gr = row0 + lr;
      if (gr < nrows)
        Y[(size_t)gr * CTOT + col0 + nc * 16 + r16] = f2bf(acc[i] * norm_s[lr]);
    }
  }
}

// ---- SpMM: Y[n,:] = relu?( (sum_{e: dst=n} Hb[src[e],:]) * norm_dst[n] + b ) ----
// bf16 gather, fp32 accumulate; output bf16 (mid pipeline) or fp32 (final).
// Edge loop unrolled x4: 4 independent gathers in flight per lane (the kernel
// is latency-bound at 1 outstanding gather: 22% VALUBusy, 35% HBM, 63% occ).

__device__ __forceinline__ void acc_row(float* acc, uint4 p) {
  acc[0] += __uint_as_float(p.x << 16);
  acc[1] += __uint_as_float(p.x & 0xffff0000u);
  acc[2] += __uint_as_float(p.y << 16);
  acc[3] += __uint_as_float(p.y & 0xffff0000u);
  acc[4] += __uint_as_float(p.z << 16);
  acc[5] += __uint_as_float(p.z & 0xffff0000u);
  acc[6] += __uint_as_float(p.w << 16);
  acc[7] += __uint_as_float(p.w & 0xffff0000u);
}

template <int F, bool RELU, bool OUT_BF16>
__global__ __launch_bounds__(256) void spmm_bf16(const u16* __restrict__ Hb,
                                                 const int* __restrict__ offs,
                                                 const int* __restrict__ deg,
                                                 const int* __restrict__ csr,
                                                 const float* __restrict__ norm_dst,
                                                 const float* __restrict__ bias,
                                                 void* __restrict__ Yv, int n) {
  constexpr int TPN = F / 8;        // threads per node (8 bf16 = 16 B per lane)
  constexpr int NPB = 256 / TPN;    // nodes per block
  int node = blockIdx.x * NPB + threadIdx.x / TPN;
  if (node >= n) return;
  int f0 = (threadIdx.x % TPN) * 8;
  int beg = offs[node];
  int end = beg + deg[node];
  const u16* __restrict__ Hp = Hb + f0;
  float acc[8] = {};
  int e = beg;
  for (; e + 4 <= end; e += 4) {
    int s0 = csr[e + 0];
    int s1 = csr[e + 1];
    int s2 = csr[e + 2];
    int s3 = csr[e + 3];
    uint4 p0 = *(const uint4*)&Hp[(size_t)s0 * F];
    uint4 p1 = *(const uint4*)&Hp[(size_t)s1 * F];
    uint4 p2 = *(const uint4*)&Hp[(size_t)s2 * F];
    uint4 p3 = *(const uint4*)&Hp[(size_t)s3 * F];
    acc_row(acc, p0);
    acc_row(acc, p1);
    acc_row(acc, p2);
    acc_row(acc, p3);
  }
  for (; e < end; e++) {
    int s = csr[e];
    uint4 p = *(const uint4*)&Hp[(size_t)s * F];
    acc_row(acc, p);
  }
  float nd = norm_dst[node];
  float o[8];
#pragma unroll
  for (int i = 0; i < 8; i++) {
    o[i] = fmaf(acc[i], nd, bias[f0 + i]);
    if (RELU) o[i] = fmaxf(o[i], 0.f);
  }
  if constexpr (OUT_BF16) {
    u16* Y = (u16*)Yv;
    uint4 pk;
    pk.x = (u32)f2bf(o[0]) | ((u32)f2bf(o[1]) << 16);
    pk.y = (u32)f2bf(o[2]) | ((u32)f2bf(o[3]) << 16);
    pk.z = (u32)f2bf(o[4]) | ((u32)f2bf(o[5]) << 16);
    pk.w = (u32)f2bf(o[6]) | ((u32)f2bf(o[7]) << 16);
    *(uint4*)&Y[(size_t)node * F + f0] = pk;
  } else {
    float* Y = (float*)Yv;
    *(float4*)&Y[(size_t)node * F + f0] = make_float4(o[0], o[1], o[2], o[3]);
    *(float4*)&Y[(size_t)node * F + f0 + 4] = make_float4(o[4], o[5], o[6], o[7]);
  }
}

// ---------------- driver ----------------

extern "C" void kernel_launch(void* const* d_in, const int* in_sizes, int n_in,
                              void* d_out, int out_size, void* d_ws, size_t ws_size,
                              hipStream_t stream) {
  const int N = NNODES;
  const int E = NEDGES;
  const float* W1 = (const float*)d_in[9];
  const float* b1 = (const float*)d_in[10];
  const float* W2 = (const float*)d_in[11];
  const float* b2 = (const float*)d_in[12];

  char* ws = (char*)d_ws;
  size_t off = 0;
  auto alloc = [&](size_t bytes) -> void* {
    void* p = ws + off;
    off += (bytes + 255) & ~(size_t)255;
    return p;
  };
  int* deg_src = (int*)alloc((size_t)N * 4);
  int* deg_dst = (int*)alloc((size_t)N * 4);
  float* norm_src = (float*)alloc((size_t)N * 4);
  float* norm_dst = (float*)alloc((size_t)N * 4);
  int* offs = (int*)alloc((size_t)N * 4);
  u32* boff = (u32*)alloc((size_t)NBUK * 4);
  u32* bcount = (u32*)alloc((size_t)NBUK * 4);
  int* csr = (int*)alloc((size_t)E * 4);
  u16* H = (u16*)alloc((size_t)N * FHID * 2);      // 25.6 MB bf16 gemm output
  u16* T = (u16*)alloc((size_t)N * FHID * 2);      // 25.6 MB bf16 spmm1 output

  // aliases: part (NSL2*NBUK u32 = 391KB) on H; pe (E u32 = 6.4MB) on T.
  // Both are dead before gemm1/spmm1 write H/T (all CSR kernels precede them).
  u32* part = (u32*)H;
  u32* pe = (u32*)T;

  const int nb = (N + 255) / 256;       // 391
  const int gemm_rb = (N + 63) / 64;    // 1563

  for (int g = 0; g < 3; g++) {
    const float* feat = (const float*)d_in[3 * g + 0];
    const int* src = (const int*)d_in[3 * g + 1];
    const int* dst = (const int*)d_in[3 * g + 2];
    float* zout = (float*)d_out + (size_t)g * N * FOUT;

    // ---- CSR build: bucket partition (2 edge passes + localized placement) ----
    zero_kernel<<<(N / 4 + 255) / 256, 256, 0, stream>>>((int4*)deg_src, N / 4);
    bucket_hist_kernel<<<NSL2, 256, 0, stream>>>(src, dst, part, deg_src, E);
    scan_part_kernel<<<1, 512, 0, stream>>>(part, boff, bcount);
    scatter_kernel<<<NSL2, 256, 0, stream>>>(src, dst, part, boff, pe, E);
    bucket_csr_kernel<<<NBUK, 256, 0, stream>>>(pe, boff, bcount, csr, offs, deg_dst,
                                                norm_dst, N);
    norm_src_kernel<<<nb, 256, 0, stream>>>(deg_src, norm_src, N);

    // ---- layer 1: H = bf16((feat @ W1) * norm_src) ; T = bf16(relu(spmm(H)*nd + b1)) ----
    gemm_mfma<FHID, false><<<dim3(gemm_rb, FHID / 64), 256, 0, stream>>>(
        feat, W1, norm_src, H, N);
    {
      constexpr int NPB = 256 / (FHID / 8);  // 16 nodes/block
      spmm_bf16<FHID, true, true><<<(N + NPB - 1) / NPB, 256, 0, stream>>>(
          H, offs, deg_dst, csr, norm_dst, b1, T, N);
    }

    // ---- layer 2: H = bf16((T @ W2) * norm_src) ; z = spmm(H)*nd + b2 (fp32) ----
    gemm_mfma<FOUT, true><<<dim3(gemm_rb, FOUT / 64), 256, 0, stream>>>(
        T, W2, norm_src, H, N);
    {
      constexpr int NPB = 256 / (FOUT / 8);  // 32 nodes/block
      spmm_bf16<FOUT, false, false><<<(N + NPB - 1) / NPB, 256, 0, stream>>>(
          H, offs, deg_dst, csr, norm_dst, b2, zout, N);
    }
  }
}

// Round 5
// 829.280 us; speedup vs baseline: 1.7685x; 1.1564x over previous
//
#include <hip/hip_runtime.h>

#define NNODES 100000
#define NEDGES 1600000
#define FIN 128
#define FHID 128
#define FOUT 64

typedef unsigned short u16;
typedef unsigned char u8;
typedef unsigned int u32;
typedef __attribute__((ext_vector_type(8))) short short8;
typedef __attribute__((ext_vector_type(4))) float floatx4;

__device__ __forceinline__ u16 f2bf(float f) {
  u32 u = __float_as_uint(f);
  u32 r = (u + 0x7fffu + ((u >> 16) & 1u)) >> 16;   // RNE
  return (u16)r;
}

// ---------------- CSR build: two-level bucket partition ----------------
// Buckets of 256 nodes (node>>8, NBUK=391). One histogram pass with TWO LDS
// histograms (dst buckets for CSR, src buckets for out-degree) -- zero global
// atomics (round-4 PMC: 1.6M deg_src atomics = 50MB HBM writeback, 23Gop/s
// atomic-rate wall, 68us). Scatter places dst-packed edges (u32) and src low
// bytes (u8) into bucket-major order; per-bucket kernels finish locally.

#define NBUK 391                       // ceil(100000/256)
#define NSL2 250
#define SLICE2 (NEDGES / NSL2)         // 6400, divisible by 4

// pass 1: per-slice bucket histograms of dst AND src (both LDS-only)
__global__ __launch_bounds__(256) void bucket_hist_kernel(const int* __restrict__ src,
                                                          const int* __restrict__ dst,
                                                          u32* __restrict__ part,
                                                          u32* __restrict__ part_src, int E) {
  __shared__ u32 hd[NBUK], hs[NBUK];
  const int s = blockIdx.x;
  for (int i = threadIdx.x; i < NBUK; i += 256) { hd[i] = 0; hs[i] = 0; }
  __syncthreads();
  const int e0 = s * SLICE2, e1 = min(e0 + SLICE2, E);
  const int i0 = e0 >> 2, i1 = e1 >> 2;
  for (int i = i0 + threadIdx.x; i < i1; i += 256) {
    int4 dv = ((const int4*)dst)[i];
    int4 sv = ((const int4*)src)[i];
    atomicAdd(&hd[(u32)dv.x >> 8], 1u);
    atomicAdd(&hd[(u32)dv.y >> 8], 1u);
    atomicAdd(&hd[(u32)dv.z >> 8], 1u);
    atomicAdd(&hd[(u32)dv.w >> 8], 1u);
    atomicAdd(&hs[(u32)sv.x >> 8], 1u);
    atomicAdd(&hs[(u32)sv.y >> 8], 1u);
    atomicAdd(&hs[(u32)sv.z >> 8], 1u);
    atomicAdd(&hs[(u32)sv.w >> 8], 1u);
  }
  __syncthreads();
  for (int i = threadIdx.x; i < NBUK; i += 256) {
    part[(size_t)s * NBUK + i] = hd[i];
    part_src[(size_t)s * NBUK + i] = hs[i];
  }
}

// scan: table[s][b] -> per-slice local prefix; boff[b]=bucket base; bcount[b]=total
// grid(2): block 0 scans the dst table, block 1 the src table.
__global__ __launch_bounds__(512) void scan_part_kernel(u32* __restrict__ part_d,
                                                        u32* __restrict__ boff_d,
                                                        u32* __restrict__ bcount_d,
                                                        u32* __restrict__ part_s,
                                                        u32* __restrict__ boff_s,
                                                        u32* __restrict__ bcount_s) {
  u32* __restrict__ part = blockIdx.x ? part_s : part_d;
  u32* __restrict__ boff = blockIdx.x ? boff_s : boff_d;
  u32* __restrict__ bcount = blockIdx.x ? bcount_s : bcount_d;
  const int b = threadIdx.x;
  u32 run = 0;
  if (b < NBUK) {
#pragma unroll 5
    for (int s = 0; s < NSL2; s++) {
      u32 v = part[(size_t)s * NBUK + b];   // coalesced across threads
      part[(size_t)s * NBUK + b] = run;
      run += v;
    }
  }
  __shared__ u32 sh[512];
  sh[threadIdx.x] = (b < NBUK) ? run : 0;
  __syncthreads();
  for (int d = 1; d < 512; d <<= 1) {
    u32 t = (threadIdx.x >= d) ? sh[threadIdx.x - d] : 0;
    __syncthreads();
    sh[threadIdx.x] += t;
    __syncthreads();
  }
  if (b < NBUK) {
    boff[b] = sh[threadIdx.x] - run;  // exclusive over buckets
    bcount[b] = run;
  }
}

// pass 2: scatter packed (src<<8)|(dst&255) into dst-bucket-major order,
// and src low bytes (u8) into src-bucket-major order.
__global__ __launch_bounds__(256) void scatter_kernel(const int* __restrict__ src,
                                                      const int* __restrict__ dst,
                                                      const u32* __restrict__ part,
                                                      const u32* __restrict__ boff,
                                                      const u32* __restrict__ part_src,
                                                      const u32* __restrict__ boff_src,
                                                      u32* __restrict__ pe,
                                                      u8* __restrict__ pes, int E) {
  __shared__ u32 cur[NBUK], curs[NBUK];
  const int s = blockIdx.x;
  for (int i = threadIdx.x; i < NBUK; i += 256) {
    cur[i] = part[(size_t)s * NBUK + i] + boff[i];
    curs[i] = part_src[(size_t)s * NBUK + i] + boff_src[i];
  }
  __syncthreads();
  const int e0 = s * SLICE2, e1 = min(e0 + SLICE2, E);
  const int i0 = e0 >> 2, i1 = e1 >> 2;
  for (int i = i0 + threadIdx.x; i < i1; i += 256) {
    int4 sv = ((const int4*)src)[i];
    int4 dv = ((const int4*)dst)[i];
    u32 p;
    p = atomicAdd(&cur[(u32)dv.x >> 8], 1u); pe[p] = ((u32)sv.x << 8) | ((u32)dv.x & 255u);
    p = atomicAdd(&cur[(u32)dv.y >> 8], 1u); pe[p] = ((u32)sv.y << 8) | ((u32)dv.y & 255u);
    p = atomicAdd(&cur[(u32)dv.z >> 8], 1u); pe[p] = ((u32)sv.z << 8) | ((u32)dv.z & 255u);
    p = atomicAdd(&cur[(u32)dv.w >> 8], 1u); pe[p] = ((u32)sv.w << 8) | ((u32)dv.w & 255u);
    p = atomicAdd(&curs[(u32)sv.x >> 8], 1u); pes[p] = (u8)((u32)sv.x & 255u);
    p = atomicAdd(&curs[(u32)sv.y >> 8], 1u); pes[p] = (u8)((u32)sv.y & 255u);
    p = atomicAdd(&curs[(u32)sv.z >> 8], 1u); pes[p] = (u8)((u32)sv.z & 255u);
    p = atomicAdd(&curs[(u32)sv.w >> 8], 1u); pes[p] = (u8)((u32)sv.w & 255u);
  }
}

// pass 3: per-bucket localized CSR build + offs/deg/norm_dst
__global__ __launch_bounds__(256) void bucket_csr_kernel(const u32* __restrict__ pe,
                                                         const u32* __restrict__ boff,
                                                         const u32* __restrict__ bcount,
                                                         int* __restrict__ csr,
                                                         int* __restrict__ offs,
                                                         int* __restrict__ deg_dst,
                                                         float* __restrict__ norm_dst, int n) {
  const int b = blockIdx.x;
  const int beg = (int)boff[b];
  const int cnt = (int)bcount[b];
  __shared__ int h[256], loc[256];
  const int t = threadIdx.x;
  h[t] = 0;
  __syncthreads();
  for (int i = t; i < cnt; i += 256) atomicAdd(&h[pe[beg + i] & 255u], 1);
  __syncthreads();
  const int myc = h[t];
  loc[t] = myc;
  __syncthreads();
  for (int d = 1; d < 256; d <<= 1) {
    int v = (t >= d) ? loc[t - d] : 0;
    __syncthreads();
    loc[t] += v;
    __syncthreads();
  }
  const int start = beg + loc[t] - myc;   // exclusive within bucket
  const int node = b * 256 + t;
  if (node < n) {
    offs[node] = start;
    deg_dst[node] = myc;
    norm_dst[node] = rsqrtf(fmaxf((float)myc, 1.0f));
  }
  __syncthreads();
  h[t] = start;          // cursors
  __syncthreads();
  for (int i = t; i < cnt; i += 256) {
    u32 v = pe[beg + i];
    int p = atomicAdd(&h[v & 255u], 1);
    csr[p] = (int)(v >> 8);     // writes localized to this bucket's ~16KB segment
  }
}

// per-bucket out-degree count from src low bytes -> norm_src (no global atomics)
__global__ __launch_bounds__(256) void bucket_count_src_kernel(const u8* __restrict__ pes,
                                                               const u32* __restrict__ boff,
                                                               const u32* __restrict__ bcount,
                                                               float* __restrict__ norm_src,
                                                               int n) {
  const int b = blockIdx.x;
  const int beg = (int)boff[b];
  const int cnt = (int)bcount[b];
  __shared__ int h[256];
  h[threadIdx.x] = 0;
  __syncthreads();
  for (int i = threadIdx.x; i < cnt; i += 256) atomicAdd(&h[pes[beg + i]], 1);
  __syncthreads();
  const int node = b * 256 + threadIdx.x;
  if (node < n) norm_src[node] = rsqrtf(fmaxf((float)h[threadIdx.x], 1.0f));
}

// ---- MFMA GEMM: Yb[n,c] = bf16( norm[n] * sum_k X[n,k] * W[k,c] ) ----
// 64x64 tile, K=128 in LDS (bf16, padded stride 136 -> 4-bank row rotation).
// 4 waves x 16 rows; A-frags in regs; mfma_f32_16x16x32_bf16, fp32 accum.

#define XP 136   // padded LDS row stride in u16

template <int CTOT, bool IN_BF16>
__global__ __launch_bounds__(256) void gemm_mfma(const void* __restrict__ Xv,
                                                 const float* __restrict__ W,
                                                 const float* __restrict__ norm,
                                                 u16* __restrict__ Y, int nrows) {
  __shared__ u16 Xs[64 * XP];   // 17408 B
  __shared__ u16 Wt[64 * XP];   // 17408 B, Wt[n][k] = W[k][col0+n]
  __shared__ float norm_s[64];
  const int tid = threadIdx.x;
  const int row0 = blockIdx.x * 64;
  const int col0 = blockIdx.y * 64;

  // stage X tile (64 rows x 128 k) as bf16
  if constexpr (IN_BF16) {
    const u16* X = (const u16*)Xv;
    for (int i = tid; i < 64 * 16; i += 256) {       // 16 uint4 per row
      int r = i >> 4, k8 = (i & 15) * 8;
      int gr = row0 + r;
      uint4 v = make_uint4(0u, 0u, 0u, 0u);
      if (gr < nrows) v = *(const uint4*)&X[(size_t)gr * 128 + k8];
      *(uint4*)&Xs[r * XP + k8] = v;
    }
  } else {
    const float* X = (const float*)Xv;
    for (int i = tid; i < 64 * 32; i += 256) {       // 32 float4 per row
      int r = i >> 5, k4 = (i & 31) * 4;
      int gr = row0 + r;
      ushort4 o = make_ushort4(0, 0, 0, 0);
      if (gr < nrows) {
        float4 v = *(const float4*)&X[(size_t)gr * 128 + k4];
        o.x = f2bf(v.x); o.y = f2bf(v.y); o.z = f2bf(v.z); o.w = f2bf(v.w);
      }
      *(ushort4*)&Xs[r * XP + k4] = o;
    }
  }
  // stage W tile transposed (64 cols x 128 k) as bf16
  for (int i = tid; i < 128 * 16; i += 256) {        // K x 16 float4-groups
    int k = i >> 4, c4 = (i & 15) * 4;
    float4 v = *(const float4*)&W[(size_t)k * CTOT + col0 + c4];
    Wt[(c4 + 0) * XP + k] = f2bf(v.x);
    Wt[(c4 + 1) * XP + k] = f2bf(v.y);
    Wt[(c4 + 2) * XP + k] = f2bf(v.z);
    Wt[(c4 + 3) * XP + k] = f2bf(v.w);
  }
  if (tid < 64) norm_s[tid] = (row0 + tid < nrows) ? norm[row0 + tid] : 0.f;
  __syncthreads();

  const int w = tid >> 6, lane = tid & 63;
  const int quad = lane >> 4, r16 = lane & 15;
  const int arow = w * 16 + r16;   // A-fragment row within tile

  short8 a[4];
#pragma unroll
  for (int kc = 0; kc < 4; kc++)
    a[kc] = *(const short8*)&Xs[arow * XP + kc * 32 + quad * 8];

#pragma unroll
  for (int nc = 0; nc < 4; nc++) {
    floatx4 acc = {0.f, 0.f, 0.f, 0.f};
#pragma unroll
    for (int kc = 0; kc < 4; kc++) {
      short8 b = *(const short8*)&Wt[(nc * 16 + r16) * XP + kc * 32 + quad * 8];
      acc = __builtin_amdgcn_mfma_f32_16x16x32_bf16(a[kc], b, acc, 0, 0, 0);
    }
#pragma unroll
    for (int i = 0; i < 4; i++) {
      int lr = w * 16 + quad * 4 + i;     // C/D: row = quad*4+reg, col = r16
      int gr = row0 + lr;
      if (gr < nrows)
        Y[(size_t)gr * CTOT + col0 + nc * 16 + r16] = f2bf(acc[i] * norm_s[lr]);
    }
  }
}

// ---- SpMM: Y[n,:] = relu?( (sum_{e: dst=n} Hb[src[e],:]) * norm_dst[n] + b ) ----
// bf16 gather, fp32 accumulate; output bf16 (mid pipeline) or fp32 (final).
// Edge loop unrolled x4: 4 independent gathers in flight per lane.

__device__ __forceinline__ void acc_row(float* acc, uint4 p) {
  acc[0] += __uint_as_float(p.x << 16);
  acc[1] += __uint_as_float(p.x & 0xffff0000u);
  acc[2] += __uint_as_float(p.y << 16);
  acc[3] += __uint_as_float(p.y & 0xffff0000u);
  acc[4] += __uint_as_float(p.z << 16);
  acc[5] += __uint_as_float(p.z & 0xffff0000u);
  acc[6] += __uint_as_float(p.w << 16);
  acc[7] += __uint_as_float(p.w & 0xffff0000u);
}

template <int F, bool RELU, bool OUT_BF16>
__global__ __launch_bounds__(256) void spmm_bf16(const u16* __restrict__ Hb,
                                                 const int* __restrict__ offs,
                                                 const int* __restrict__ deg,
                                                 const int* __restrict__ csr,
                                                 const float* __restrict__ norm_dst,
                                                 const float* __restrict__ bias,
                                                 void* __restrict__ Yv, int n) {
  constexpr int TPN = F / 8;        // threads per node (8 bf16 = 16 B per lane)
  constexpr int NPB = 256 / TPN;    // nodes per block
  int node = blockIdx.x * NPB + threadIdx.x / TPN;
  if (node >= n) return;
  int f0 = (threadIdx.x % TPN) * 8;
  int beg = offs[node];
  int end = beg + deg[node];
  const u16* __restrict__ Hp = Hb + f0;
  float acc[8] = {};
  int e = beg;
  for (; e + 4 <= end; e += 4) {
    int s0 = csr[e + 0];
    int s1 = csr[e + 1];
    int s2 = csr[e + 2];
    int s3 = csr[e + 3];
    uint4 p0 = *(const uint4*)&Hp[(size_t)s0 * F];
    uint4 p1 = *(const uint4*)&Hp[(size_t)s1 * F];
    uint4 p2 = *(const uint4*)&Hp[(size_t)s2 * F];
    uint4 p3 = *(const uint4*)&Hp[(size_t)s3 * F];
    acc_row(acc, p0);
    acc_row(acc, p1);
    acc_row(acc, p2);
    acc_row(acc, p3);
  }
  for (; e < end; e++) {
    int s = csr[e];
    uint4 p = *(const uint4*)&Hp[(size_t)s * F];
    acc_row(acc, p);
  }
  float nd = norm_dst[node];
  float o[8];
#pragma unroll
  for (int i = 0; i < 8; i++) {
    o[i] = fmaf(acc[i], nd, bias[f0 + i]);
    if (RELU) o[i] = fmaxf(o[i], 0.f);
  }
  if constexpr (OUT_BF16) {
    u16* Y = (u16*)Yv;
    uint4 pk;
    pk.x = (u32)f2bf(o[0]) | ((u32)f2bf(o[1]) << 16);
    pk.y = (u32)f2bf(o[2]) | ((u32)f2bf(o[3]) << 16);
    pk.z = (u32)f2bf(o[4]) | ((u32)f2bf(o[5]) << 16);
    pk.w = (u32)f2bf(o[6]) | ((u32)f2bf(o[7]) << 16);
    *(uint4*)&Y[(size_t)node * F + f0] = pk;
  } else {
    float* Y = (float*)Yv;
    *(float4*)&Y[(size_t)node * F + f0] = make_float4(o[0], o[1], o[2], o[3]);
    *(float4*)&Y[(size_t)node * F + f0 + 4] = make_float4(o[4], o[5], o[6], o[7]);
  }
}

// ---------------- driver ----------------

extern "C" void kernel_launch(void* const* d_in, const int* in_sizes, int n_in,
                              void* d_out, int out_size, void* d_ws, size_t ws_size,
                              hipStream_t stream) {
  const int N = NNODES;
  const int E = NEDGES;
  const float* W1 = (const float*)d_in[9];
  const float* b1 = (const float*)d_in[10];
  const float* W2 = (const float*)d_in[11];
  const float* b2 = (const float*)d_in[12];

  char* ws = (char*)d_ws;
  size_t off = 0;
  auto alloc = [&](size_t bytes) -> void* {
    void* p = ws + off;
    off += (bytes + 255) & ~(size_t)255;
    return p;
  };
  int* deg_dst = (int*)alloc((size_t)N * 4);
  float* norm_src = (float*)alloc((size_t)N * 4);
  float* norm_dst = (float*)alloc((size_t)N * 4);
  int* offs = (int*)alloc((size_t)N * 4);
  u32* boff = (u32*)alloc((size_t)NBUK * 4);
  u32* bcount = (u32*)alloc((size_t)NBUK * 4);
  u32* boff_s = (u32*)alloc((size_t)NBUK * 4);
  u32* bcount_s = (u32*)alloc((size_t)NBUK * 4);
  int* csr = (int*)alloc((size_t)E * 4);
  u16* H = (u16*)alloc((size_t)N * FHID * 2);      // 25.6 MB bf16 gemm output
  u16* T = (u16*)alloc((size_t)N * FHID * 2);      // 25.6 MB bf16 spmm1 output

  // aliases inside H (25.6 MB), all dead before gemm1 writes H:
  //   part      (NSL2*NBUK u32 = 391 KB)
  //   part_src  (NSL2*NBUK u32 = 391 KB)
  //   pes       (E u8 = 1.6 MB)
  // alias inside T: pe (E u32 = 6.4 MB), dead before spmm1 writes T.
  u32* part = (u32*)H;
  u32* part_src = part + (size_t)NSL2 * NBUK;
  u8* pes = (u8*)(part_src + (size_t)NSL2 * NBUK);
  u32* pe = (u32*)T;

  const int gemm_rb = (N + 63) / 64;    // 1563

  for (int g = 0; g < 3; g++) {
    const float* feat = (const float*)d_in[3 * g + 0];
    const int* src = (const int*)d_in[3 * g + 1];
    const int* dst = (const int*)d_in[3 * g + 2];
    float* zout = (float*)d_out + (size_t)g * N * FOUT;

    // ---- CSR build: bucket partition, zero global atomics ----
    bucket_hist_kernel<<<NSL2, 256, 0, stream>>>(src, dst, part, part_src, E);
    scan_part_kernel<<<2, 512, 0, stream>>>(part, boff, bcount, part_src, boff_s, bcount_s);
    scatter_kernel<<<NSL2, 256, 0, stream>>>(src, dst, part, boff, part_src, boff_s,
                                             pe, pes, E);
    bucket_csr_kernel<<<NBUK, 256, 0, stream>>>(pe, boff, bcount, csr, offs, deg_dst,
                                                norm_dst, N);
    bucket_count_src_kernel<<<NBUK, 256, 0, stream>>>(pes, boff_s, bcount_s, norm_src, N);

    // ---- layer 1: H = bf16((feat @ W1) * norm_src) ; T = bf16(relu(spmm(H)*nd + b1)) ----
    gemm_mfma<FHID, false><<<dim3(gemm_rb, FHID / 64), 256, 0, stream>>>(
        feat, W1, norm_src, H, N);
    {
      constexpr int NPB = 256 / (FHID / 8);  // 16 nodes/block
      spmm_bf16<FHID, true, true><<<(N + NPB - 1) / NPB, 256, 0, stream>>>(
          H, offs, deg_dst, csr, norm_dst, b1, T, N);
    }

    // ---- layer 2: H = bf16((T @ W2) * norm_src) ; z = spmm(H)*nd + b2 (fp32) ----
    gemm_mfma<FOUT, true><<<dim3(gemm_rb, FOUT / 64), 256, 0, stream>>>(
        T, W2, norm_src, H, N);
    {
      constexpr int NPB = 256 / (FOUT / 8);  // 32 nodes/block
      spmm_bf16<FOUT, false, false><<<(N + NPB - 1) / NPB, 256, 0, stream>>>(
          H, offs, deg_dst, csr, norm_dst, b2, zout, N);
    }
  }
}

// Round 6
// 713.301 us; speedup vs baseline: 2.0560x; 1.1626x over previous
//
#include <hip/hip_runtime.h>

#define NNODES 100000
#define NEDGES 1600000
#define FIN 128
#define FHID 128
#define FOUT 64

typedef unsigned short u16;
typedef unsigned char u8;
typedef unsigned int u32;
typedef __attribute__((ext_vector_type(8))) short short8;
typedef __attribute__((ext_vector_type(4))) float floatx4;

#define NBUK 391                       // ceil(100000/256)
#define NSL2 250
#define SLICE2 (NEDGES / NSL2)         // 6400, divisible by 4
#define SP ((size_t)NSL2 * NBUK)       // part table elems per graph
#define NH16 ((size_t)NNODES * FHID)   // u16 elems per graph H/T slice

__device__ __forceinline__ u16 f2bf(float f) {
  u32 u = __float_as_uint(f);
  u32 r = (u + 0x7fffu + ((u >> 16) & 1u)) >> 16;   // RNE
  return (u16)r;
}

__device__ __forceinline__ const int* sel(const int* a, const int* b, const int* c, int z) {
  return z == 0 ? a : (z == 1 ? b : c);
}

// ---------------- CSR build: two-level bucket partition, batched over graphs ----
// blockIdx.z = graph. Buckets of 256 nodes (node>>8). One histogram pass with
// TWO LDS histograms (dst for CSR, src for out-degree) -- zero global atomics.
// Scatter places dst-packed edges (u32) and src low bytes (u8) bucket-major;
// per-bucket kernels finish locally. part/part_src/pes alias H[z]; pe aliases T[z].

__global__ __launch_bounds__(256) void bucket_hist_kernel(
    const int* s0, const int* s1, const int* s2,
    const int* d0, const int* d1, const int* d2,
    u16* __restrict__ Hbase, int E) {
  const int z = blockIdx.z;
  const int* __restrict__ src = sel(s0, s1, s2, z);
  const int* __restrict__ dst = sel(d0, d1, d2, z);
  u32* __restrict__ part = (u32*)(Hbase + (size_t)z * NH16);
  u32* __restrict__ part_src = part + SP;
  __shared__ u32 hd[NBUK], hs[NBUK];
  const int s = blockIdx.x;
  for (int i = threadIdx.x; i < NBUK; i += 256) { hd[i] = 0; hs[i] = 0; }
  __syncthreads();
  const int e0 = s * SLICE2, e1 = min(e0 + SLICE2, E);
  const int i0 = e0 >> 2, i1 = e1 >> 2;
  for (int i = i0 + threadIdx.x; i < i1; i += 256) {
    int4 dv = ((const int4*)dst)[i];
    int4 sv = ((const int4*)src)[i];
    atomicAdd(&hd[(u32)dv.x >> 8], 1u);
    atomicAdd(&hd[(u32)dv.y >> 8], 1u);
    atomicAdd(&hd[(u32)dv.z >> 8], 1u);
    atomicAdd(&hd[(u32)dv.w >> 8], 1u);
    atomicAdd(&hs[(u32)sv.x >> 8], 1u);
    atomicAdd(&hs[(u32)sv.y >> 8], 1u);
    atomicAdd(&hs[(u32)sv.z >> 8], 1u);
    atomicAdd(&hs[(u32)sv.w >> 8], 1u);
  }
  __syncthreads();
  for (int i = threadIdx.x; i < NBUK; i += 256) {
    part[(size_t)s * NBUK + i] = hd[i];
    part_src[(size_t)s * NBUK + i] = hs[i];
  }
}

// grid(2,1,z): block.x 0 scans the dst table, 1 the src table.
__global__ __launch_bounds__(512) void scan_part_kernel(u16* __restrict__ Hbase,
                                                        u32* __restrict__ boff_d,
                                                        u32* __restrict__ bcount_d,
                                                        u32* __restrict__ boff_s,
                                                        u32* __restrict__ bcount_s) {
  const int z = blockIdx.z;
  u32* base = (u32*)(Hbase + (size_t)z * NH16);
  u32* __restrict__ part = blockIdx.x ? base + SP : base;
  u32* __restrict__ boff = (blockIdx.x ? boff_s : boff_d) + (size_t)z * NBUK;
  u32* __restrict__ bcount = (blockIdx.x ? bcount_s : bcount_d) + (size_t)z * NBUK;
  const int b = threadIdx.x;
  u32 run = 0;
  if (b < NBUK) {
#pragma unroll 5
    for (int s = 0; s < NSL2; s++) {
      u32 v = part[(size_t)s * NBUK + b];   // coalesced across threads
      part[(size_t)s * NBUK + b] = run;
      run += v;
    }
  }
  __shared__ u32 sh[512];
  sh[threadIdx.x] = (b < NBUK) ? run : 0;
  __syncthreads();
  for (int d = 1; d < 512; d <<= 1) {
    u32 t = (threadIdx.x >= d) ? sh[threadIdx.x - d] : 0;
    __syncthreads();
    sh[threadIdx.x] += t;
    __syncthreads();
  }
  if (b < NBUK) {
    boff[b] = sh[threadIdx.x] - run;  // exclusive over buckets
    bcount[b] = run;
  }
}

__global__ __launch_bounds__(256) void scatter_kernel(
    const int* s0, const int* s1, const int* s2,
    const int* d0, const int* d1, const int* d2,
    u16* __restrict__ Hbase, u16* __restrict__ Tbase,
    const u32* __restrict__ boff_d, const u32* __restrict__ boff_src, int E) {
  const int z = blockIdx.z;
  const int* __restrict__ src = sel(s0, s1, s2, z);
  const int* __restrict__ dst = sel(d0, d1, d2, z);
  const u32* __restrict__ part = (const u32*)(Hbase + (size_t)z * NH16);
  const u32* __restrict__ part_src = part + SP;
  u8* __restrict__ pes = (u8*)(part_src + SP);
  u32* __restrict__ pe = (u32*)(Tbase + (size_t)z * NH16);
  const u32* __restrict__ boff = boff_d + (size_t)z * NBUK;
  const u32* __restrict__ boff_s = boff_src + (size_t)z * NBUK;
  __shared__ u32 cur[NBUK], curs[NBUK];
  const int s = blockIdx.x;
  for (int i = threadIdx.x; i < NBUK; i += 256) {
    cur[i] = part[(size_t)s * NBUK + i] + boff[i];
    curs[i] = part_src[(size_t)s * NBUK + i] + boff_s[i];
  }
  __syncthreads();
  const int e0 = s * SLICE2, e1 = min(e0 + SLICE2, E);
  const int i0 = e0 >> 2, i1 = e1 >> 2;
  for (int i = i0 + threadIdx.x; i < i1; i += 256) {
    int4 sv = ((const int4*)src)[i];
    int4 dv = ((const int4*)dst)[i];
    u32 p;
    p = atomicAdd(&cur[(u32)dv.x >> 8], 1u); pe[p] = ((u32)sv.x << 8) | ((u32)dv.x & 255u);
    p = atomicAdd(&cur[(u32)dv.y >> 8], 1u); pe[p] = ((u32)sv.y << 8) | ((u32)dv.y & 255u);
    p = atomicAdd(&cur[(u32)dv.z >> 8], 1u); pe[p] = ((u32)sv.z << 8) | ((u32)dv.z & 255u);
    p = atomicAdd(&cur[(u32)dv.w >> 8], 1u); pe[p] = ((u32)sv.w << 8) | ((u32)dv.w & 255u);
    p = atomicAdd(&curs[(u32)sv.x >> 8], 1u); pes[p] = (u8)((u32)sv.x & 255u);
    p = atomicAdd(&curs[(u32)sv.y >> 8], 1u); pes[p] = (u8)((u32)sv.y & 255u);
    p = atomicAdd(&curs[(u32)sv.z >> 8], 1u); pes[p] = (u8)((u32)sv.z & 255u);
    p = atomicAdd(&curs[(u32)sv.w >> 8], 1u); pes[p] = (u8)((u32)sv.w & 255u);
  }
}

__global__ __launch_bounds__(256) void bucket_csr_kernel(const u16* __restrict__ Tbase,
                                                         const u32* __restrict__ boffb,
                                                         const u32* __restrict__ bcountb,
                                                         int* __restrict__ csrb,
                                                         int* __restrict__ offsb,
                                                         int* __restrict__ degb,
                                                         float* __restrict__ ndb, int n) {
  const int z = blockIdx.z;
  const u32* __restrict__ pe = (const u32*)(Tbase + (size_t)z * NH16);
  int* __restrict__ csr = csrb + (size_t)z * NEDGES;
  int* __restrict__ offs = offsb + (size_t)z * NNODES;
  int* __restrict__ deg_dst = degb + (size_t)z * NNODES;
  float* __restrict__ norm_dst = ndb + (size_t)z * NNODES;
  const u32* boff = boffb + (size_t)z * NBUK;
  const u32* bcount = bcountb + (size_t)z * NBUK;
  const int b = blockIdx.x;
  const int beg = (int)boff[b];
  const int cnt = (int)bcount[b];
  __shared__ int h[256], loc[256];
  const int t = threadIdx.x;
  h[t] = 0;
  __syncthreads();
  for (int i = t; i < cnt; i += 256) atomicAdd(&h[pe[beg + i] & 255u], 1);
  __syncthreads();
  const int myc = h[t];
  loc[t] = myc;
  __syncthreads();
  for (int d = 1; d < 256; d <<= 1) {
    int v = (t >= d) ? loc[t - d] : 0;
    __syncthreads();
    loc[t] += v;
    __syncthreads();
  }
  const int start = beg + loc[t] - myc;   // exclusive within bucket
  const int node = b * 256 + t;
  if (node < n) {
    offs[node] = start;
    deg_dst[node] = myc;
    norm_dst[node] = rsqrtf(fmaxf((float)myc, 1.0f));
  }
  __syncthreads();
  h[t] = start;          // cursors
  __syncthreads();
  for (int i = t; i < cnt; i += 256) {
    u32 v = pe[beg + i];
    int p = atomicAdd(&h[v & 255u], 1);
    csr[p] = (int)(v >> 8);     // writes localized to this bucket's ~16KB segment
  }
}

__global__ __launch_bounds__(256) void bucket_count_src_kernel(const u16* __restrict__ Hbase,
                                                               const u32* __restrict__ boffb,
                                                               const u32* __restrict__ bcountb,
                                                               float* __restrict__ nsb, int n) {
  const int z = blockIdx.z;
  const u32* partb = (const u32*)(Hbase + (size_t)z * NH16);
  const u8* __restrict__ pes = (const u8*)(partb + 2 * SP);
  const u32* boff = boffb + (size_t)z * NBUK;
  const u32* bcount = bcountb + (size_t)z * NBUK;
  float* __restrict__ norm_src = nsb + (size_t)z * NNODES;
  const int b = blockIdx.x;
  const int beg = (int)boff[b];
  const int cnt = (int)bcount[b];
  __shared__ int h[256];
  h[threadIdx.x] = 0;
  __syncthreads();
  for (int i = threadIdx.x; i < cnt; i += 256) atomicAdd(&h[pes[beg + i]], 1);
  __syncthreads();
  const int node = b * 256 + threadIdx.x;
  if (node < n) norm_src[node] = rsqrtf(fmaxf((float)h[threadIdx.x], 1.0f));
}

// ---- MFMA GEMM: Yb[n,c] = bf16( norm[n] * sum_k X[n,k] * W[k,c] ) ----
// 64x64 tile, K=128 in LDS (bf16, padded stride 136). 4 waves x 16 rows;
// A-frags in regs; mfma_f32_16x16x32_bf16, fp32 accum. blockIdx.z = graph.

#define XP 136   // padded LDS row stride in u16

template <int CTOT, bool IN_BF16>
__global__ __launch_bounds__(256) void gemm_mfma(const void* X0, const void* X1,
                                                 const void* X2,
                                                 const float* __restrict__ W,
                                                 const float* __restrict__ normb,
                                                 u16* __restrict__ Yb, int nrows) {
  const int z = blockIdx.z;
  const void* __restrict__ Xv = z == 0 ? X0 : (z == 1 ? X1 : X2);
  const float* __restrict__ norm = normb + (size_t)z * NNODES;
  u16* __restrict__ Y = Yb + (size_t)z * NNODES * CTOT;
  __shared__ u16 Xs[64 * XP];   // 17408 B
  __shared__ u16 Wt[64 * XP];   // 17408 B, Wt[n][k] = W[k][col0+n]
  __shared__ float norm_s[64];
  const int tid = threadIdx.x;
  const int row0 = blockIdx.x * 64;
  const int col0 = blockIdx.y * 64;

  if constexpr (IN_BF16) {
    const u16* X = (const u16*)Xv;
    for (int i = tid; i < 64 * 16; i += 256) {       // 16 uint4 per row
      int r = i >> 4, k8 = (i & 15) * 8;
      int gr = row0 + r;
      uint4 v = make_uint4(0u, 0u, 0u, 0u);
      if (gr < nrows) v = *(const uint4*)&X[(size_t)gr * 128 + k8];
      *(uint4*)&Xs[r * XP + k8] = v;
    }
  } else {
    const float* X = (const float*)Xv;
    for (int i = tid; i < 64 * 32; i += 256) {       // 32 float4 per row
      int r = i >> 5, k4 = (i & 31) * 4;
      int gr = row0 + r;
      ushort4 o = make_ushort4(0, 0, 0, 0);
      if (gr < nrows) {
        float4 v = *(const float4*)&X[(size_t)gr * 128 + k4];
        o.x = f2bf(v.x); o.y = f2bf(v.y); o.z = f2bf(v.z); o.w = f2bf(v.w);
      }
      *(ushort4*)&Xs[r * XP + k4] = o;
    }
  }
  for (int i = tid; i < 128 * 16; i += 256) {        // K x 16 float4-groups
    int k = i >> 4, c4 = (i & 15) * 4;
    float4 v = *(const float4*)&W[(size_t)k * CTOT + col0 + c4];
    Wt[(c4 + 0) * XP + k] = f2bf(v.x);
    Wt[(c4 + 1) * XP + k] = f2bf(v.y);
    Wt[(c4 + 2) * XP + k] = f2bf(v.z);
    Wt[(c4 + 3) * XP + k] = f2bf(v.w);
  }
  if (tid < 64) norm_s[tid] = (row0 + tid < nrows) ? norm[row0 + tid] : 0.f;
  __syncthreads();

  const int w = tid >> 6, lane = tid & 63;
  const int quad = lane >> 4, r16 = lane & 15;
  const int arow = w * 16 + r16;

  short8 a[4];
#pragma unroll
  for (int kc = 0; kc < 4; kc++)
    a[kc] = *(const short8*)&Xs[arow * XP + kc * 32 + quad * 8];

#pragma unroll
  for (int nc = 0; nc < 4; nc++) {
    floatx4 acc = {0.f, 0.f, 0.f, 0.f};
#pragma unroll
    for (int kc = 0; kc < 4; kc++) {
      short8 b = *(const short8*)&Wt[(nc * 16 + r16) * XP + kc * 32 + quad * 8];
      acc = __builtin_amdgcn_mfma_f32_16x16x32_bf16(a[kc], b, acc, 0, 0, 0);
    }
#pragma unroll
    for (int i = 0; i < 4; i++) {
      int lr = w * 16 + quad * 4 + i;     // C/D: row = quad*4+reg, col = r16
      int gr = row0 + lr;
      if (gr < nrows)
        Y[(size_t)gr * CTOT + col0 + nc * 16 + r16] = f2bf(acc[i] * norm_s[lr]);
    }
  }
}

// ---- SpMM: Y[n,:] = relu?( (sum_{e: dst=n} Hb[src[e],:]) * norm_dst[n] + b ) ----
// bf16 gather, fp32 accumulate. Two-stage software pipeline of 4-edge batches:
// batch k+1's csr+row loads issue while batch k accumulates -> ~8 gathers in
// flight per lane at ~60 VGPR (keeps full wave occupancy). blockIdx.z = graph.

__device__ __forceinline__ void acc_row(float* acc, uint4 p) {
  acc[0] += __uint_as_float(p.x << 16);
  acc[1] += __uint_as_float(p.x & 0xffff0000u);
  acc[2] += __uint_as_float(p.y << 16);
  acc[3] += __uint_as_float(p.y & 0xffff0000u);
  acc[4] += __uint_as_float(p.z << 16);
  acc[5] += __uint_as_float(p.z & 0xffff0000u);
  acc[6] += __uint_as_float(p.w << 16);
  acc[7] += __uint_as_float(p.w & 0xffff0000u);
}

template <int F, bool RELU, bool OUT_BF16>
__global__ __launch_bounds__(256) void spmm_bf16(const u16* __restrict__ Hbase,
                                                 const int* __restrict__ offsb,
                                                 const int* __restrict__ degb,
                                                 const int* __restrict__ csrb,
                                                 const float* __restrict__ ndb,
                                                 const float* __restrict__ bias,
                                                 void* __restrict__ Yv, int n) {
  const int z = blockIdx.z;
  const u16* __restrict__ Hb = Hbase + (size_t)z * NNODES * F;
  const int* __restrict__ offs = offsb + (size_t)z * NNODES;
  const int* __restrict__ deg = degb + (size_t)z * NNODES;
  const int* __restrict__ csr = csrb + (size_t)z * NEDGES;
  const float* __restrict__ norm_dst = ndb + (size_t)z * NNODES;
  constexpr int TPN = F / 8;        // threads per node (8 bf16 = 16 B per lane)
  constexpr int NPB = 256 / TPN;    // nodes per block
  int node = blockIdx.x * NPB + threadIdx.x / TPN;
  if (node >= n) return;
  int f0 = (threadIdx.x % TPN) * 8;
  int beg = offs[node];
  int end = beg + deg[node];
  const u16* __restrict__ Hp = Hb + f0;
  float acc[8] = {};
  int e = beg;
  int nfull = (end - beg) >> 2;
  if (nfull > 0) {
    int sv[4]; uint4 p[4];
#pragma unroll
    for (int j = 0; j < 4; j++) sv[j] = csr[e + j];
#pragma unroll
    for (int j = 0; j < 4; j++) p[j] = *(const uint4*)&Hp[(size_t)sv[j] * F];
    for (int b = 1; b < nfull; b++) {
      e += 4;
      int s2[4]; uint4 q[4];
#pragma unroll
      for (int j = 0; j < 4; j++) s2[j] = csr[e + j];
#pragma unroll
      for (int j = 0; j < 4; j++) q[j] = *(const uint4*)&Hp[(size_t)s2[j] * F];
#pragma unroll
      for (int j = 0; j < 4; j++) acc_row(acc, p[j]);
#pragma unroll
      for (int j = 0; j < 4; j++) p[j] = q[j];
    }
#pragma unroll
    for (int j = 0; j < 4; j++) acc_row(acc, p[j]);
    e += 4;
  }
  for (; e < end; e++) {
    int s = csr[e];
    uint4 p = *(const uint4*)&Hp[(size_t)s * F];
    acc_row(acc, p);
  }
  float nd = norm_dst[node];
  float o[8];
#pragma unroll
  for (int i = 0; i < 8; i++) {
    o[i] = fmaf(acc[i], nd, bias[f0 + i]);
    if (RELU) o[i] = fmaxf(o[i], 0.f);
  }
  if constexpr (OUT_BF16) {
    u16* Y = (u16*)Yv + (size_t)z * NNODES * F;
    uint4 pk;
    pk.x = (u32)f2bf(o[0]) | ((u32)f2bf(o[1]) << 16);
    pk.y = (u32)f2bf(o[2]) | ((u32)f2bf(o[3]) << 16);
    pk.z = (u32)f2bf(o[4]) | ((u32)f2bf(o[5]) << 16);
    pk.w = (u32)f2bf(o[6]) | ((u32)f2bf(o[7]) << 16);
    *(uint4*)&Y[(size_t)node * F + f0] = pk;
  } else {
    float* Y = (float*)Yv + (size_t)z * NNODES * F;
    *(float4*)&Y[(size_t)node * F + f0] = make_float4(o[0], o[1], o[2], o[3]);
    *(float4*)&Y[(size_t)node * F + f0 + 4] = make_float4(o[4], o[5], o[6], o[7]);
  }
}

// ---------------- driver ----------------
// All phases batched over the 3 graphs via gridDim.z=3 (33 launches -> 9),
// guarded by ws_size; falls back to the proven per-graph sequential path.

extern "C" void kernel_launch(void* const* d_in, const int* in_sizes, int n_in,
                              void* d_out, int out_size, void* d_ws, size_t ws_size,
                              hipStream_t stream) {
  const int N = NNODES;
  const int E = NEDGES;
  const float* W1 = (const float*)d_in[9];
  const float* b1 = (const float*)d_in[10];
  const float* W2 = (const float*)d_in[11];
  const float* b2 = (const float*)d_in[12];

  const size_t HBYTES = NH16 * 2;   // 25.6 MB per graph

  auto need_for = [&](size_t NG) -> size_t {
    size_t o = 0;
    auto al = [&](size_t b) { o = (o + b + 255) & ~(size_t)255; };
    al(NG * N * 4);        // deg_dst
    al(NG * N * 4);        // norm_src
    al(NG * N * 4);        // norm_dst
    al(NG * N * 4);        // offs
    al(NG * NBUK * 4);     // boff
    al(NG * NBUK * 4);     // bcount
    al(NG * NBUK * 4);     // boff_s
    al(NG * NBUK * 4);     // bcount_s
    al(NG * (size_t)E * 4);// csr
    al(NG * HBYTES);       // H
    al(NG * HBYTES);       // T
    return o;
  };
  const bool batched = ws_size >= need_for(3);
  const size_t NG = batched ? 3 : 1;

  char* ws = (char*)d_ws;
  size_t off = 0;
  auto alloc = [&](size_t bytes) -> void* {
    void* p = ws + off;
    off += (bytes + 255) & ~(size_t)255;
    return p;
  };
  int* deg_dst = (int*)alloc(NG * N * 4);
  float* norm_src = (float*)alloc(NG * N * 4);
  float* norm_dst = (float*)alloc(NG * N * 4);
  int* offs = (int*)alloc(NG * N * 4);
  u32* boff = (u32*)alloc(NG * NBUK * 4);
  u32* bcount = (u32*)alloc(NG * NBUK * 4);
  u32* boff_s = (u32*)alloc(NG * NBUK * 4);
  u32* bcount_s = (u32*)alloc(NG * NBUK * 4);
  int* csr = (int*)alloc(NG * (size_t)E * 4);
  u16* H = (u16*)alloc(NG * HBYTES);
  u16* T = (u16*)alloc(NG * HBYTES);

  const int gemm_rb = (N + 63) / 64;    // 1563
  const int nb1 = (N + 15) / 16;        // 6250 (F=128: 16 nodes/block)
  const int nb2 = (N + 31) / 32;        // 3125 (F=64:  32 nodes/block)

  auto run = [&](const int* s0, const int* s1, const int* s2,
                 const int* d0, const int* d1, const int* d2,
                 const float* f0, const float* f1, const float* f2,
                 const void* x20, const void* x21, const void* x22,
                 void* zoutv, unsigned gz) {
    bucket_hist_kernel<<<dim3(NSL2, 1, gz), 256, 0, stream>>>(s0, s1, s2, d0, d1, d2, H, E);
    scan_part_kernel<<<dim3(2, 1, gz), 512, 0, stream>>>(H, boff, bcount, boff_s, bcount_s);
    scatter_kernel<<<dim3(NSL2, 1, gz), 256, 0, stream>>>(s0, s1, s2, d0, d1, d2,
                                                          H, T, boff, boff_s, E);
    bucket_csr_kernel<<<dim3(NBUK, 1, gz), 256, 0, stream>>>(T, boff, bcount, csr, offs,
                                                             deg_dst, norm_dst, N);
    bucket_count_src_kernel<<<dim3(NBUK, 1, gz), 256, 0, stream>>>(H, boff_s, bcount_s,
                                                                   norm_src, N);
    // layer 1: H = bf16((feat @ W1)*norm_src); T = bf16(relu(spmm(H)*nd + b1))
    gemm_mfma<FHID, false><<<dim3(gemm_rb, FHID / 64, gz), 256, 0, stream>>>(
        f0, f1, f2, W1, norm_src, H, N);
    spmm_bf16<FHID, true, true><<<dim3(nb1, 1, gz), 256, 0, stream>>>(
        H, offs, deg_dst, csr, norm_dst, b1, T, N);
    // layer 2: H = bf16((T @ W2)*norm_src); z = spmm(H)*nd + b2 (fp32)
    gemm_mfma<FOUT, true><<<dim3(gemm_rb, FOUT / 64, gz), 256, 0, stream>>>(
        x20, x21, x22, W2, norm_src, H, N);
    spmm_bf16<FOUT, false, false><<<dim3(nb2, 1, gz), 256, 0, stream>>>(
        H, offs, deg_dst, csr, norm_dst, b2, zoutv, N);
  };

  if (batched) {
    run((const int*)d_in[1], (const int*)d_in[4], (const int*)d_in[7],
        (const int*)d_in[2], (const int*)d_in[5], (const int*)d_in[8],
        (const float*)d_in[0], (const float*)d_in[3], (const float*)d_in[6],
        T, T + NH16, T + 2 * NH16,
        d_out, 3);
  } else {
    for (int g = 0; g < 3; g++) {
      const float* feat = (const float*)d_in[3 * g + 0];
      const int* src = (const int*)d_in[3 * g + 1];
      const int* dst = (const int*)d_in[3 * g + 2];
      float* zout = (float*)d_out + (size_t)g * N * FOUT;
      run(src, src, src, dst, dst, dst, feat, feat, feat, T, T, T, zout, 1);
    }
  }
}